// Round 9
// baseline (471.752 us; speedup 1.0000x reference)
//
#include <hip/hip_runtime.h>
#include <hip/hip_bf16.h>

#define HIDDEN 512
#define ATT    128
#define NB     64
#define SL     2048
#define LN_EPS 1e-3f

typedef __attribute__((ext_vector_type(8))) short short8;
typedef __attribute__((ext_vector_type(4))) float f32x4;
typedef __attribute__((ext_vector_type(2))) unsigned ux2;

__device__ __forceinline__ short f2bf(float f) {
    union { float f; unsigned u; } v; v.f = f;
    unsigned r = v.u + 0x7fffu + ((v.u >> 16) & 1u);   // RNE
    return (short)(r >> 16);
}
__device__ __forceinline__ unsigned pack2bf(float lo, float hi) {
    union { __hip_bfloat162 h; unsigned u; } v;
    v.h = __float22bfloat162_rn(make_float2(lo, hi));
    return v.u;
}
__device__ __forceinline__ float bflo(unsigned u) {
    union { unsigned x; float f; } v; v.x = u << 16; return v.f;
}
__device__ __forceinline__ float bfhi(unsigned u) {
    union { unsigned x; float f; } v; v.x = u & 0xffff0000u; return v.f;
}
__device__ __forceinline__ float tanh_fast(float x) {
    float cx = fminf(fmaxf(x, -15.f), 15.f);
    float e = __expf(2.f * cx);
    return (e - 1.f) * __builtin_amdgcn_rcpf(e + 1.f);
}
__device__ __forceinline__ f32x4 nt_load4(const float* p) {
    return __builtin_nontemporal_load((const f32x4*)p);
}
// async global->LDS DMA, 16B per lane; LDS dest = wave-uniform base + lane*16
__device__ __forceinline__ void gld_lds16(const float* g, float* lds) {
    __builtin_amdgcn_global_load_lds((const __attribute__((address_space(1))) void*)g,
                                     (__attribute__((address_space(3))) void*)lds, 16, 0, 0);
}

// ---- P0: Bp = bf16(W) pre-permuted into MFMA B-fragment order -------------
// Bp[((ks*8 + nt)*64 + lane)*8 + j] = bf16(W[h][a]),
//   h = ks*32 + (lane>>4)*8 + j, a = nt*16 + (lane&15),  ks = 0..15
__global__ void p0_wt(const float* __restrict__ W, short* __restrict__ Bp) {
    int idx = blockIdx.x * 256 + threadIdx.x;   // 65536 total
    int j = idx & 7, lane = (idx >> 3) & 63, nt = (idx >> 9) & 7, ks = idx >> 12;
    int a = nt * 16 + (lane & 15);
    int h = ks * 32 + ((lane >> 4) << 3) + j;
    Bp[idx] = f2bf(W[h * ATT + a]);
}

// ---- P1: h_att = bf16(h @ W) (fragment-permuted) + per-wave ctx partials --
// 2048 blocks x 256 thr, zero __syncthreads. Each wave owns 16 rows; per
// K-chunk of 32: {B(c) 8 L2 loads -> DMA stage(c+1) 2 async global_load_lds
// -> s_waitcnt vmcnt(2) -> MFMA(c) from LDS -> ctx partials + store}.
// stage(c+1) is awaited a FULL iteration later (counted wait, never behind
// an HBM stall in-iteration); B loads are older than the new DMAs so they
// retire without waiting on HBM. Small tile keeps ~100 VGPR + 16KB LDS ->
// high occupancy AND deep pipeline (R8 had the pipeline at half occupancy).
// Swizzle: LDS slot (row, blk) holds global 16B-block (blk ^ (row&7)).
__launch_bounds__(256, 4)
__global__ void p1_gemm_ctx(const float* __restrict__ hidden, const short* __restrict__ Bp,
                            short* __restrict__ h_att, float* __restrict__ ctx_part) {
    __shared__ __align__(16) float Asf[4][2][16 * 32];   // 16 KB, [wave][buf], fp32

    int t = threadIdx.x;
    int wave = t >> 6, lane = t & 63, quad = lane >> 4, cb = lane & 15;
    int gw = blockIdx.x * 4 + wave;          // global wave id, 0..8191
    int row0 = gw * 16;

    f32x4 acc[8];
    #pragma unroll
    for (int nt = 0; nt < 8; ++nt) acc[nt] = (f32x4){0.f, 0.f, 0.f, 0.f};

    int lr = lane >> 3;                      // 0..7 row-in-group
    int lc = lane & 7;                       // 16B-block within 32-col chunk
    int blkp = lc ^ lr;                      // swizzled source block (row&7 == lr)
    const float* g0 = hidden + (size_t)(row0 + lr) * HIDDEN + blkp * 4;
    float (*my)[16 * 32] = Asf[wave];
    const short8* Bp8 = (const short8*)Bp + lane;

    auto stage = [&](int c, int buf) {
        gld_lds16(g0 + c * 32,                      &my[buf][0]);       // rows 0..7
        gld_lds16(g0 + (size_t)8 * HIDDEN + c * 32, &my[buf][8 * 32]);  // rows 8..15
    };

    stage(0, 0);

    for (int c = 0; c < 16; ++c) {
        int buf = c & 1;

        // 1. B-fragment loads (L2-resident Bp) — oldest in queue
        short8 b8[8];
        #pragma unroll
        for (int nt = 0; nt < 8; ++nt)
            b8[nt] = Bp8[((size_t)c * 8 + nt) * 64];
        __builtin_amdgcn_sched_barrier(0);

        // 2. async stage of next chunk into the other buffer
        if (c < 15) stage(c + 1, buf ^ 1);
        __builtin_amdgcn_sched_barrier(0);

        // 3. counted wait: retire stage(c) + prior ctx store + B loads;
        //    stage(c+1)'s 2 DMAs stay in flight across all of compute
        if (c < 15) { asm volatile("s_waitcnt vmcnt(2)" ::: "memory"); }
        else        { asm volatile("s_waitcnt vmcnt(0)" ::: "memory"); }
        __builtin_amdgcn_sched_barrier(0);

        // 4. MFMA on buf(c): ds_read (XOR-unswizzle), cvt_pk, 8 MFMA
        {
            int lb0 = quad * 2;
            int o0 = ((lb0 ^ (cb & 7)) << 2);
            int o1 = (((lb0 + 1) ^ (cb & 7)) << 2);
            f32x4 alo = *(const f32x4*)&my[buf][cb * 32 + o0];
            f32x4 ahi = *(const f32x4*)&my[buf][cb * 32 + o1];
            union { short8 s8; unsigned u[4]; } ap;
            ap.u[0] = pack2bf(alo.x, alo.y); ap.u[1] = pack2bf(alo.z, alo.w);
            ap.u[2] = pack2bf(ahi.x, ahi.y); ap.u[3] = pack2bf(ahi.z, ahi.w);
            #pragma unroll
            for (int nt = 0; nt < 8; ++nt)
                acc[nt] = __builtin_amdgcn_mfma_f32_16x16x32_bf16(ap.s8, b8[nt], acc[nt], 0, 0, 0);
        }

        // 5. ctx column partials from the staged fp32 tile
        {
            f32x4 f0 = *(const f32x4*)&my[buf][lr * 32 + (blkp << 2)];
            f32x4 f1 = *(const f32x4*)&my[buf][(lr + 8) * 32 + (blkp << 2)];
            float s[4] = { f0.x + f1.x, f0.y + f1.y, f0.z + f1.z, f0.w + f1.w };
            #pragma unroll
            for (int j = 0; j < 4; ++j) {
                s[j] += __shfl_xor(s[j], 8);
                s[j] += __shfl_xor(s[j], 16);
                s[j] += __shfl_xor(s[j], 32);
            }
            if (lane < 8) {
                float* cp = ctx_part + (size_t)gw * HIDDEN + c * 32 + lane * 4;
                __builtin_nontemporal_store((f32x4){s[0], s[1], s[2], s[3]}, (f32x4*)cp);
            }
        }
    }

    // epilogue: fragment-permuted coalesced store, bf16 pair-packed, nt
    // value (row=row0+quad*4+j, col=nt*16+cb) at uint2 index (gw*8+nt)*64+lane
    ux2* hp = (ux2*)h_att;
    size_t base = (size_t)gw * 8 * 64 + lane;
    #pragma unroll
    for (int nt = 0; nt < 8; ++nt) {
        ux2 p;
        p.x = pack2bf(acc[nt][0], acc[nt][1]);
        p.y = pack2bf(acc[nt][2], acc[nt][3]);
        __builtin_nontemporal_store(p, &hp[base + (size_t)nt * 64]);
    }
}

// ---- P2: uatt[b][a] = (sum_chunks ctx_part / SL) . U[:,a] -----------------
// ctx_part is per-wave: 128 chunks of [512] per batch (16-row waves).
__launch_bounds__(256)
__global__ void p2_uatt(const float* __restrict__ ctx_part, const float* __restrict__ U,
                        float* __restrict__ uatt) {
    int b = blockIdx.x, t = threadIdx.x;
    __shared__ float cs[HIDDEN];
    __shared__ float ds[256];
    float s0 = 0.f, s1 = 0.f;
    #pragma unroll 8
    for (int c = 0; c < 128; ++c) {
        const float* base = ctx_part + (size_t)(b * 128 + c) * HIDDEN;
        s0 += __builtin_nontemporal_load(base + t);
        s1 += __builtin_nontemporal_load(base + t + 256);
    }
    cs[t] = s0; cs[t + 256] = s1;
    __syncthreads();
    int a = t & 127, h0 = (t >> 7) * 256;
    float d = 0.f;
    #pragma unroll 8
    for (int h = 0; h < 256; ++h) d += cs[h0 + h] * U[(size_t)(h0 + h) * ATT + a];
    ds[t] = d;
    __syncthreads();
    if (t < 128) uatt[b * ATT + t] = (ds[t] + ds[t + 128]) * (1.f / SL);
}

// ---- P3: scores[r] = v . tanh(h_att[r] + uatt[b])  (fragment layout) ------
// 2048 blocks x 256; wave gw reads back exactly the uint2 fragments it wrote.
__launch_bounds__(256)
__global__ void p3_scores(const short* __restrict__ h_att, const float* __restrict__ v_a,
                          const float* __restrict__ uatt, float* __restrict__ scores) {
    int t = threadIdx.x, bx = blockIdx.x;
    int wave = t >> 6, lane = t & 63, quad = lane >> 4, cb = lane & 15;
    int gw = bx * 4 + wave;                  // 0..8191
    int b = gw >> 7;                         // 128 waves per batch

    float uv[8], vv[8];
    #pragma unroll
    for (int nt = 0; nt < 8; ++nt) {
        uv[nt] = uatt[b * ATT + nt * 16 + cb];
        vv[nt] = v_a[nt * 16 + cb];
    }

    const ux2* hp = (const ux2*)h_att;
    size_t base = (size_t)gw * 8 * 64 + lane;

    ux2 f[8];
    #pragma unroll
    for (int nt = 0; nt < 8; ++nt)
        f[nt] = __builtin_nontemporal_load(&hp[base + (size_t)nt * 64]);
    float r[4] = {0.f, 0.f, 0.f, 0.f};
    #pragma unroll
    for (int nt = 0; nt < 8; ++nt) {
        r[0] += vv[nt] * tanh_fast(bflo(f[nt].x) + uv[nt]);
        r[1] += vv[nt] * tanh_fast(bfhi(f[nt].x) + uv[nt]);
        r[2] += vv[nt] * tanh_fast(bflo(f[nt].y) + uv[nt]);
        r[3] += vv[nt] * tanh_fast(bfhi(f[nt].y) + uv[nt]);
    }
    #pragma unroll
    for (int j = 0; j < 4; ++j) {
        r[j] += __shfl_xor(r[j], 1);
        r[j] += __shfl_xor(r[j], 2);
        r[j] += __shfl_xor(r[j], 4);
        r[j] += __shfl_xor(r[j], 8);
    }
    if (cb == 0) {
        #pragma unroll
        for (int j = 0; j < 4; ++j)
            scores[gw * 16 + quad * 4 + j] = r[j];
    }
}

// ---- P4: softmax over L (in place, in d_out's attn region) ----------------
__launch_bounds__(256)
__global__ void p4_softmax(float* __restrict__ attn) {
    int b = blockIdx.x, t = threadIdx.x;
    float* p = attn + b * SL;
    __shared__ float red[256];
    float v[8];
    float m = -1e30f;
    #pragma unroll
    for (int i = 0; i < 8; ++i) { v[i] = p[t + i * 256]; m = fmaxf(m, v[i]); }
    red[t] = m; __syncthreads();
    for (int s = 128; s > 0; s >>= 1) { if (t < s) red[t] = fmaxf(red[t], red[t + s]); __syncthreads(); }
    m = red[0]; __syncthreads();
    float sum = 0.f;
    #pragma unroll
    for (int i = 0; i < 8; ++i) { v[i] = __expf(v[i] - m); sum += v[i]; }
    red[t] = sum; __syncthreads();
    for (int s = 128; s > 0; s >>= 1) { if (t < s) red[t] += red[t + s]; __syncthreads(); }
    float inv = 1.f / red[0];
    #pragma unroll
    for (int i = 0; i < 8; ++i) p[t + i * 256] = v[i] * inv;
}

// ---- P5: attended partials: att_part[c][b][h] = sum_{l in chunk} attn*h ----
__launch_bounds__(256)
__global__ void p5_attended(const float* __restrict__ hidden, const float* __restrict__ attn,
                            float* __restrict__ att_part) {
    int b = blockIdx.y, c = blockIdx.x, t = threadIdx.x;
    __shared__ float w_s[128];
    __shared__ f32x4 red_s[128];
    if (t < 128) w_s[t] = attn[b * SL + c * 128 + t];
    __syncthreads();
    int cg = t & 127, half = t >> 7;
    const float* hp = hidden + ((size_t)b * SL + c * 128 + half * 64) * HIDDEN + cg * 4;
    f32x4 a = {0.f, 0.f, 0.f, 0.f};
    #pragma unroll 4
    for (int l = 0; l < 64; ++l) {
        float w = w_s[half * 64 + l];
        const f32x4 g = nt_load4(hp + (size_t)l * HIDDEN);
        a.x += w * g.x; a.y += w * g.y; a.z += w * g.z; a.w += w * g.w;
    }
    if (half) red_s[cg] = a;
    __syncthreads();
    if (!half) {
        f32x4 r = red_s[cg];
        a.x += r.x; a.y += r.y; a.z += r.z; a.w += r.w;
        __builtin_nontemporal_store(a, (f32x4*)(att_part + ((size_t)(c * NB + b)) * HIDDEN + cg * 4));
    }
}

// ---- P6: reduce att_part chunks + LayerNorm -------------------------------
__launch_bounds__(256)
__global__ void p6_ln(const float* __restrict__ att_part, const float* __restrict__ gamma,
                      const float* __restrict__ beta, float* __restrict__ out) {
    int b = blockIdx.x, t = threadIdx.x;
    float x0 = 0.f, x1 = 0.f;
    #pragma unroll
    for (int c = 0; c < 16; ++c) {
        size_t base = (size_t)(c * NB + b) * HIDDEN;
        x0 += __builtin_nontemporal_load(att_part + base + t);
        x1 += __builtin_nontemporal_load(att_part + base + t + 256);
    }
    __shared__ float rs[256], rq[256];
    rs[t] = x0 + x1; rq[t] = x0 * x0 + x1 * x1;
    __syncthreads();
    for (int s = 128; s > 0; s >>= 1) {
        if (t < s) { rs[t] += rs[t + s]; rq[t] += rq[t + s]; }
        __syncthreads();
    }
    float mean = rs[0] * (1.f / HIDDEN);
    float var = rq[0] * (1.f / HIDDEN) - mean * mean;
    float r = rsqrtf(var + LN_EPS);
    out[b * HIDDEN + t]       = (x0 - mean) * r * gamma[t] + beta[t];
    out[b * HIDDEN + t + 256] = (x1 - mean) * r * gamma[t + 256] + beta[t + 256];
}

extern "C" void kernel_launch(void* const* d_in, const int* in_sizes, int n_in,
                              void* d_out, int out_size, void* d_ws, size_t ws_size,
                              hipStream_t stream) {
    const float* hidden = (const float*)d_in[0];
    const float* W      = (const float*)d_in[1];
    const float* U      = (const float*)d_in[2];
    const float* v_a    = (const float*)d_in[3];
    const float* gamma  = (const float*)d_in[4];
    const float* beta   = (const float*)d_in[5];

    float* out  = (float*)d_out;          // [64][512]
    float* attn = out + NB * HIDDEN;      // [64][2048] scores -> softmax in place

    // ws layout (every buffer fully written before read; no memset needed)
    short* h_att    = (short*)d_ws;                                        // [8192][8][64] ux2 bf16 (fragment-permuted)
    float* ctx_part = (float*)((char*)d_ws + (size_t)NB * SL * ATT * 2);   // [8192][512] per-wave
    float* att_part = ctx_part + (size_t)8192 * HIDDEN;                    // [16][64][512]
    float* uatt     = att_part + (size_t)16 * NB * HIDDEN;                 // [64][128]
    short* Bp       = (short*)(uatt + NB * ATT);                           // [16][8][64][8] bf16 (frag-permuted W)

    p0_wt<<<256, 256, 0, stream>>>(W, Bp);
    p1_gemm_ctx<<<(NB * SL) / 64, 256, 0, stream>>>(hidden, Bp, h_att, ctx_part);
    p2_uatt<<<NB, 256, 0, stream>>>(ctx_part, U, uatt);
    p3_scores<<<(NB * SL) / 64, 256, 0, stream>>>(h_att, v_a, uatt, attn);
    p4_softmax<<<NB, 256, 0, stream>>>(attn);
    p5_attended<<<dim3(16, NB), 256, 0, stream>>>(hidden, attn, att_part);
    p6_ln<<<NB, 256, 0, stream>>>(att_part, gamma, beta, out);
}